// Round 9
// baseline (43.580 us; speedup 1.0000x reference)
//
#include <hip/hip_runtime.h>

#define DISP_RANGE 10
#define OUT_D 21
#define A_ 9
#define D_ 128
#define HW_ 4096   // 64*64
#define CH 32      // rows per staged chunk

typedef float f32x4 __attribute__((ext_vector_type(4)));   // NT-store-compatible

// Role 0 (uh): out[b,0,a,k,h,w] = wt_k * sum_{dd in win_k} uh[b,a,dd-32+h,h,w]  (0 if row OOB)
// Role 1 (vw): out[b,1,a,k,h,w] = wt_k * sum_{dd in win_k} vw[b,a,dd-32+w,h,w]  (0 if row OOB)
//
// Block = (b, role*a, h-group of 4), 512 threads = 8 waves (wave = (kg, hh)).
// ALL global traffic is 1 KB contiguous wave-requests:
//   loads:  row r's (h0..h0+3, all w) span = 1 KB, reg-staged (float4/lane)
//           then ds_write -> LDS chunk (CH rows), double-buffered; next chunk's
//           loads issue before the barrier -> HBM latency hides under compute.
//   stores: (k, h0..h0+3, all w) 1 KB spans from an LDS-transposed tile, NT.
// OOB rows are zero-staged, so compute needs only the chunk-membership mask.
// vw diagonal LDS read addr = 257*w + const -> bank-conflict-free.

template<int AD, int ROLE> struct P {
    static constexpr int L   = 2 * DISP_RANGE * AD + 1;   // 21/41/61/81
    static constexpr int S0  = 64 - DISP_RANGE * AD;      // 54/44/34/24
    // staged rows relative to rbase: role0 rr = (dd-S0)+hh < L+3
    //                                role1 rr = (dd-S0)+w  < L+63
    static constexpr int NR  = (ROLE == 0) ? (L + 3) : (L + 63);
    static constexpr int NCH = (NR + CH - 1) / CH;        // 1..5
};

template<int AD, int ROLE>
__device__ __forceinline__ void load_chunk(
    const float* __restrict__ in, size_t plane, int h0, int ch,
    int wid, int lane, f32x4* r)
{
    using p = P<AD, ROLE>;
    const int rbase = (p::S0 - 32) + (ROLE == 0 ? h0 : 0);
#pragma unroll
    for (int i = 0; i < 4; ++i) {
        const int j    = wid + 8 * i;          // row within chunk, 0..31
        const int rr   = ch * CH + j;
        const int grow = rbase + rr;           // global d-row (wave-uniform)
        r[i] = (f32x4)(0.f);
        if (rr < p::NR && grow >= 0 && grow < D_)
            r[i] = *reinterpret_cast<const f32x4*>(
                in + plane + (size_t)grow * HW_ + (size_t)(h0 * 64 + lane * 4));
    }
}

__device__ __forceinline__ void write_chunk(float* buf, int wid, int lane,
                                            const f32x4* r)
{
#pragma unroll
    for (int i = 0; i < 4; ++i) {
        const int j = wid + 8 * i;
        *reinterpret_cast<f32x4*>(buf + j * 256 + lane * 4) = r[i];
    }
}

template<int AD, int ROLE, int KG>
__device__ __forceinline__ void compute_chunk(
    const float* buf, int ch, int hh, int w, float* acc)
{
    using p = P<AD, ROLE>;
    constexpr int K0 = (KG == 0) ? 0 : 11;
    constexpr int K1 = (KG == 0) ? 11 : 21;
#pragma unroll
    for (int k = K0; k < K1; ++k) {
        const int s = (k * p::L) / OUT_D;
        const int e = ((k + 1) * p::L + OUT_D - 1) / OUT_D;
#pragma unroll
        for (int dd = p::S0 + s; dd < p::S0 + e; ++dd) {
            const int rrel = dd - p::S0;       // folds after unroll
            if (ROLE == 0) {
                // rr = rrel + hh spans 4 -> 1-2 chunks touch
                if (rrel + 3 >= ch * CH && rrel < ch * CH + CH) {
                    const int  j  = rrel + hh - ch * CH;
                    const bool ok = (j >= 0) && (j < CH);
                    const int  jc = j < 0 ? 0 : (j > CH - 1 ? CH - 1 : j);
                    const float v = buf[jc * 256 + hh * 64 + w];
                    acc[k - K0] += ok ? v : 0.f;
                }
            } else {
                // rr = rrel + w spans 64 -> 2-3 chunks touch
                if (rrel + 63 >= ch * CH && rrel < ch * CH + CH) {
                    const int  j  = rrel + w - ch * CH;
                    const bool ok = (j >= 0) && (j < CH);
                    const int  jc = j < 0 ? 0 : (j > CH - 1 ? CH - 1 : j);
                    const float v = buf[jc * 256 + hh * 64 + w];
                    acc[k - K0] += ok ? v : 0.f;
                }
            }
        }
    }
}

template<int AD, int ROLE, int KG>
__device__ __forceinline__ void run(
    const float* __restrict__ in, float* __restrict__ out, float* lds,
    int b, int a, int h0, int wid, int lane)
{
    using p = P<AD, ROLE>;
    constexpr int K0 = (KG == 0) ? 0 : 11;
    constexpr int NK = (KG == 0) ? 11 : 10;
    const int hh = wid & 3;                    // h = h0 + hh
    const int w  = lane;
    const size_t plane = (size_t)(b * A_ + a) * D_ * HW_;

    float acc[NK];
#pragma unroll
    for (int i = 0; i < NK; ++i) acc[i] = 0.f;

    f32x4 r[4];
    load_chunk<AD, ROLE>(in, plane, h0, 0, wid, lane, r);
#pragma unroll
    for (int ch = 0; ch < p::NCH; ++ch) {
        float* buf = lds + (ch & 1) * 8192;    // 32 KB per buffer
        write_chunk(buf, wid, lane, r);
        if (ch + 1 < p::NCH)
            load_chunk<AD, ROLE>(in, plane, h0, ch + 1, wid, lane, r);
        __syncthreads();                        // chunk ch fully written
        compute_chunk<AD, ROLE, KG>(buf, ch, hh, w, acc);
        // no 2nd barrier: buf[ch&1] reused at ch+2, and the ch+1 barrier
        // already orders all readers of ch before writers of ch+2.
    }
    __syncthreads();

    // ---- epilogue: acc -> LDS tile -> 1 KB NT stores ----
#pragma unroll
    for (int i = 0; i < NK; ++i) {
        const int k = K0 + i;
        const int s = (k * p::L) / OUT_D;
        const int e = ((k + 1) * p::L + OUT_D - 1) / OUT_D;
        lds[k * 256 + hh * 64 + w] = acc[i] * (1.f / (float)(e - s));
    }
    __syncthreads();

    const size_t ob = ((size_t)(b * 2 + ROLE) * A_ + a) * OUT_D * HW_
                    + (size_t)(h0 * 64);
#pragma unroll
    for (int it = 0; it < 3; ++it) {
        const int k = wid + 8 * it;            // 21 rows over 8 waves
        if (k < OUT_D) {
            const f32x4 v = *reinterpret_cast<const f32x4*>(lds + k * 256 + lane * 4);
            __builtin_nontemporal_store(
                v, reinterpret_cast<f32x4*>(out + ob + (size_t)k * HW_ + lane * 4));
        }
    }
}

template<int AD>
__device__ __forceinline__ void run_ad(
    const float* __restrict__ uh, const float* __restrict__ vw,
    float* __restrict__ out, float* lds,
    int b, int a, int h0, int role, int wid, int lane)
{
    const int kg = wid >> 2;                   // waves 0-3: k 0-10, 4-7: k 11-20
    if (role == 0) {
        if (kg == 0) run<AD, 0, 0>(uh, out, lds, b, a, h0, wid, lane);
        else         run<AD, 0, 1>(uh, out, lds, b, a, h0, wid, lane);
    } else {
        if (kg == 0) run<AD, 1, 0>(vw, out, lds, b, a, h0, wid, lane);
        else         run<AD, 1, 1>(vw, out, lds, b, a, h0, wid, lane);
    }
}

__global__ __launch_bounds__(512, 4) void cost_volume_kernel(
    const float* __restrict__ uh,
    const float* __restrict__ vw,
    float* __restrict__ out)
{
    __shared__ float lds[16384];               // 2 x 32 KB chunk buffers

    const int h0   = (int)blockIdx.x * 4;
    const int y    = (int)blockIdx.y;          // 0..17
    const int b    = (int)blockIdx.z;
    const int a    = (y >= A_) ? (y - A_) : y;
    const int role = (y >= A_) ? 1 : 0;
    const int t    = (int)threadIdx.x;
    const int lane = t & 63;
    const int wid  = t >> 6;

    switch (a) {
        case 3: case 4: case 5:
            run_ad<1>(uh, vw, out, lds, b, a, h0, role, wid, lane); break;
        case 2: case 6:
            run_ad<2>(uh, vw, out, lds, b, a, h0, role, wid, lane); break;
        case 1: case 7:
            run_ad<3>(uh, vw, out, lds, b, a, h0, role, wid, lane); break;
        default:   // 0, 8
            run_ad<4>(uh, vw, out, lds, b, a, h0, role, wid, lane); break;
    }
}

extern "C" void kernel_launch(void* const* d_in, const int* in_sizes, int n_in,
                              void* d_out, int out_size, void* d_ws, size_t ws_size,
                              hipStream_t stream) {
    const float* uh = (const float*)d_in[0];   // [8,9,128,64,64] f32
    const float* vw = (const float*)d_in[1];   // [8,9,128,64,64] f32
    float* out = (float*)d_out;                // [8,2,9,21,64,64] f32

    dim3 grid(16, 2 * A_, 8);   // (h-group, role*a, b) = 2304 blocks
    dim3 block(512);
    cost_volume_kernel<<<grid, block, 0, stream>>>(uh, vw, out);
}